// Round 9
// baseline (268.658 us; speedup 1.0000x reference)
//
#include <hip/hip_runtime.h>
#include <hip/hip_bf16.h>

typedef __hip_bfloat16 bf16;
typedef unsigned short ushort_t;
typedef __attribute__((ext_vector_type(8))) __bf16 bf16x8;
typedef __attribute__((ext_vector_type(4))) float f32x4;

#define DIMC 128
#define NH 8
#define HD 16
#define HSZ 128
#define WSZ 128
#define HW (HSZ*WSZ)
#define CI_PAD 160    // 147 real ext channels, padded to 160 (mult of 32)
#define KTOT (9*CI_PAD)   // 1440
#define COUT 640      // 128 q | 128 k_pan | 128 v_pan | 128 k_ms | 128 v_ms
#define PROW 130      // padded image dim (1 halo each side)
#define NPIX (PROW*PROW)
#define TW 136        // attn fp32 tile row width; interior col c at idx 4+c

static __device__ __forceinline__ float b2f(bf16 v) { return __bfloat162float(v); }
static __device__ __forceinline__ bf16 f2b(float v) { return __float2bfloat16(v); }
static __device__ __forceinline__ ushort_t f2bu(float v) {
  bf16 t = __float2bfloat16(v);
  return *reinterpret_cast<ushort_t*>(&t);
}
static __device__ __forceinline__ float u2f(unsigned int u) {
  unsigned int w = u << 16;
  float f;
  __builtin_memcpy(&f, &w, 4);
  return f;
}
static __device__ __forceinline__ float u2f_hi(unsigned int u) {
  unsigned int w = u & 0xffff0000u;
  float f;
  __builtin_memcpy(&f, &w, 4);
  return f;
}
// async global->LDS, 16B per lane; LDS dest = wave-uniform base + lane*16
static __device__ __forceinline__ void gl_lds16(const void* g, void* l) {
  __builtin_amdgcn_global_load_lds(
      (const __attribute__((address_space(1))) unsigned int*)g,
      (__attribute__((address_space(3))) unsigned int*)l, 16, 0, 0);
}

// ---------------------------------------------------------------- prep X_T (coalesced)
// y<128: interior row. y==128: zero rows 0/129. y==129: zero cols 0/129.
__global__ __launch_bounds__(256) void k_prep(
    const float* __restrict__ x, const float* __restrict__ ms,
    const float* __restrict__ lpan, const float* __restrict__ pan,
    const float* __restrict__ s, ushort_t* __restrict__ xt, int B) {
  int t = threadIdx.x;
  int y = blockIdx.y;
  int b = blockIdx.z;
  ushort_t* xtb = xt + (size_t)b * NPIX * CI_PAD;
  if (y == 128) {            // border rows: yy = 0 (x=0) or 129 (x=1)
    int yy = blockIdx.x ? 129 : 0;
    uint4 z = {0u, 0u, 0u, 0u};
    uint4* dst = (uint4*)(xtb + (size_t)yy * PROW * CI_PAD);
    for (int i = t; i < PROW * CI_PAD / 8; i += 256) dst[i] = z;
    return;
  }
  if (y == 129) {            // border cols: xx = 0 or 129, yy = 1..128
    int xx = blockIdx.x ? 129 : 0;
    uint4 z = {0u, 0u, 0u, 0u};
    for (int i = t; i < 128 * (CI_PAD / 8); i += 256) {
      int yy = 1 + i / (CI_PAD / 8);
      int q4 = i % (CI_PAD / 8);
      *(uint4*)(xtb + ((size_t)yy * PROW + xx) * CI_PAD + q4 * 8) = z;
    }
    return;
  }
  int l = t & 63;          // pixel within chunk
  int cg = t >> 6;         // channel group 0..3 (wave-uniform)
  int chunk = blockIdx.x;  // 0..1
  int p = y * WSZ + chunk * 64 + l;
  const float* xb = x + (size_t)b * 128 * HW;
  const float* msb = ms + (size_t)b * 8 * HW;

  float vals[40];
  if (cg < 3) {
    int ci0 = cg * 40;
#pragma unroll
    for (int k = 0; k < 40; k++) vals[k] = xb[(size_t)(ci0 + k) * HW + p];
  } else {  // ci 120..159
    float sv = s[b];
#pragma unroll
    for (int k = 0; k < 8; k++) vals[k] = xb[(size_t)(120 + k) * HW + p];
    float lp = lpan[(size_t)b * HW + p];
    float pn = pan[(size_t)b * HW + p];
#pragma unroll
    for (int k = 0; k < 8; k++)
      vals[8 + k] = lp * (1.f - sv) + msb[(size_t)k * HW + p] * sv;  // cond
    vals[16] = lp;
    vals[17] = pn;
    vals[18] = pn - lp;
#pragma unroll
    for (int k = 0; k < 8; k++) vals[19 + k] = msb[(size_t)k * HW + p];
#pragma unroll
    for (int k = 27; k < 40; k++) vals[k] = 0.f;
  }
  ushort_t us[40];
#pragma unroll
  for (int k = 0; k < 40; k++) us[k] = f2bu(vals[k]);
  int yy = y + 1, xx = 1 + chunk * 64 + l;
  ushort_t* dst = xtb + ((size_t)yy * PROW + xx) * CI_PAD + cg * 40;
#pragma unroll
  for (int k = 0; k < 5; k++) *(uint4*)(dst + k * 8) = *(uint4*)(us + k * 8);
}

// ---------------------------------------------------------------- pack weights (coalesced)
__global__ __launch_bounds__(256) void k_pack(
    const float* __restrict__ qw, const float* __restrict__ qb,
    const float* __restrict__ kpw, const float* __restrict__ kpb,
    const float* __restrict__ vpw, const float* __restrict__ vpb,
    const float* __restrict__ kvw, const float* __restrict__ kvb,
    const float* __restrict__ ppw, const float* __restrict__ ppb,
    const float* __restrict__ pmw, const float* __restrict__ pmb,
    ushort_t* __restrict__ wp2, ushort_t* __restrict__ wproj,
    float* __restrict__ bpack) {
  int g = blockIdx.x * 256 + threadIdx.x;
  if (g < COUT * CI_PAD) {
    int co = g / CI_PAD, ci = g % CI_PAD;
    const float* src = nullptr;
    if (ci < 147) {
      if (co < 128) {
        if (ci < 136) src = qw + ((size_t)co * 136 + ci) * 9;
      } else if (co < 256) {
        int o = co - 128;
        if (ci < 128) src = kpw + ((size_t)o * 129 + ci) * 9;
        else if (ci == 136) src = kpw + ((size_t)o * 129 + 128) * 9;
      } else if (co < 384) {
        int o = co - 256;
        if (ci < 128) src = vpw + ((size_t)o * 131 + ci) * 9;
        else if (ci >= 136 && ci <= 138) src = vpw + ((size_t)o * 131 + 128 + (ci - 136)) * 9;
      } else {
        int o = co - 384;
        if (ci < 128) src = kvw + ((size_t)o * 136 + ci) * 9;
        else if (ci >= 139) src = kvw + ((size_t)o * 136 + 128 + (ci - 139)) * 9;
      }
    }
    ushort_t* d = wp2 + (size_t)co * KTOT + ci;
#pragma unroll
    for (int tp = 0; tp < 9; tp++) d[(size_t)tp * CI_PAD] = f2bu(src ? src[tp] : 0.f);
  }
  if (g < 2 * 128 * 128) {   // proj weights
    int sp = g >> 14;
    int rem = g & 16383;
    wproj[g] = f2bu(sp ? pmw[rem] : ppw[rem]);
  }
  if (g < COUT) {
    float bv;
    if (g < 128) bv = qb[g];
    else if (g < 256) bv = kpb[g - 128];
    else if (g < 384) bv = vpb[g - 256];
    else bv = kvb[g - 384];
    bpack[g] = bv;
  } else if (g < COUT + 256) {
    int o = g - COUT;
    bpack[g] = (o < 128) ? ppb[o] : pmb[o - 128];
  }
}

// ---------------------------------------------------------------- MFMA implicit GEMM conv
// K order (ky,kx,ci) is contiguous in BOTH wp2 and xt: per ky, a 480-elem run.
// Flat 45 BK=32 steps; LDS double-buffer; ONE barrier per step.
__global__ __launch_bounds__(256) void k_conv_mfma(
    const ushort_t* __restrict__ xt, const ushort_t* __restrict__ wp2,
    const float* __restrict__ bpack, bf16* __restrict__ Y, int B) {
  __shared__ ushort_t As[2][128 * 32];   // [buf][co][k]
  __shared__ ushort_t Bs[2][128 * 32];   // [buf][px][k]
  int tid = threadIdx.x;
  int lane = tid & 63;
  int wid = tid >> 6;
  int y = blockIdx.x;              // image row
  int co0 = blockIdx.y * 128;
  int b = blockIdx.z;
  const ushort_t* xtb = xt + (size_t)b * NPIX * CI_PAD;

  int wm = (wid >> 1) * 64, wn = (wid & 1) * 64;
  int l15 = lane & 15, q = lane >> 4, kq = q * 8;
  int lrow = lane >> 2;
  int lq = lane & 3;

  f32x4 acc[4][4];
#pragma unroll
  for (int i = 0; i < 4; i++)
#pragma unroll
    for (int j = 0; j < 4; j++) acc[i][j] = (f32x4){0.f, 0.f, 0.f, 0.f};

  // staging sources (advance +32 per step; B gets a row fix-up at ky wrap)
  const ushort_t* aPtr = wp2 + (size_t)(co0 + wid * 32 + lrow) * KTOT + lq * 8;
  const ushort_t* bPtr = xtb + ((size_t)y * PROW + wid * 32 + lrow) * CI_PAD + lq * 8;

  auto stage = [&](int buf, const ushort_t* aP, const ushort_t* bP) {
    gl_lds16(aP, &As[buf][(wid * 32) * 32]);
    gl_lds16(aP + (size_t)16 * KTOT, &As[buf][(wid * 32 + 16) * 32]);
    gl_lds16(bP, &Bs[buf][(wid * 32) * 32]);
    gl_lds16(bP + (size_t)16 * CI_PAD, &Bs[buf][(wid * 32 + 16) * 32]);
  };

  stage(0, aPtr, bPtr);
  int segc = 0;
  for (int step = 0; step < 45; ++step) {
    int buf = step & 1;
    __syncthreads();   // drains stage(step) vmcnt; also guards buf^1 reuse
    if (step + 1 < 45) {
      aPtr += 32;
      bPtr += 32;
      if (++segc == 15) { segc = 0; bPtr += PROW * CI_PAD - 480; }
      stage(buf ^ 1, aPtr, bPtr);
    }
    bf16x8 af[4], bv[4];
#pragma unroll
    for (int t = 0; t < 4; t++)
      af[t] = *(const bf16x8*)&As[buf][(wm + t * 16 + l15) * 32 + kq];
#pragma unroll
    for (int t = 0; t < 4; t++)
      bv[t] = *(const bf16x8*)&Bs[buf][(wn + t * 16 + l15) * 32 + kq];
#pragma unroll
    for (int i = 0; i < 4; i++)
#pragma unroll
      for (int j = 0; j < 4; j++)
        acc[i][j] = __builtin_amdgcn_mfma_f32_16x16x32_bf16(af[i], bv[j],
                                                            acc[i][j], 0, 0, 0);
  }

#pragma unroll
  for (int i = 0; i < 4; i++) {
    int corow = co0 + wm + i * 16 + q * 4;
#pragma unroll
    for (int j = 0; j < 4; j++) {
      int px = wn + j * 16 + l15;
      size_t base = ((size_t)b * COUT + corow) * HW + y * WSZ + px;
#pragma unroll
      for (int r = 0; r < 4; r++)
        Y[base + (size_t)r * HW] = f2b(acc[i][j][r] + bpack[corow + r]);
    }
  }
}

// ---------------------------------------------------------------- depthwise + attention
// fp32 LDS tile [16 ch][6 rows][TW=136]; interior col c at idx 4+c, halos 3/132.
// Thread: 2 adjacent px; float2 packed math. Output transposed bf16 for proj.
__global__ __launch_bounds__(256) void k_attn(
    const bf16* __restrict__ Y, const float* __restrict__ dep_w,
    const float* __restrict__ dep_b, ushort_t* __restrict__ att_t, int B) {
  __shared__ float tile[16 * 6 * TW];
  int tid = threadIdx.x;
  int sp = blockIdx.y >> 3, n = blockIdx.y & 7;
  int b = blockIdx.z;
  int y0 = blockIdx.x * 4;
  int qch = n * HD;
  int kch = (sp ? 384 : 128) + n * HD;
  int vch = (sp ? 512 : 256) + n * HD;
  const bf16* Yb = Y + (size_t)b * COUT * HW;

  int r = tid >> 6;          // row in tile 0..3
  int c0 = (tid & 63) * 2;   // col 0..126
  int p0 = (y0 + r) * WSZ + c0;

  auto stage = [&](int ch0) {
    for (int i = tid; i < 16 * 6 * 16; i += 256) {
      int ch = i / 96;
      int rem = i - ch * 96;
      int rr = rem >> 4, c8 = rem & 15;
      int yy = y0 - 1 + rr;
      float4 f0 = {0.f, 0.f, 0.f, 0.f}, f1 = {0.f, 0.f, 0.f, 0.f};
      if (yy >= 0 && yy < HSZ) {
        uint4 v = *(const uint4*)(Yb + (size_t)(ch0 + ch) * HW + yy * WSZ + c8 * 8);
        f0.x = u2f(v.x); f0.y = u2f_hi(v.x);
        f0.z = u2f(v.y); f0.w = u2f_hi(v.y);
        f1.x = u2f(v.z); f1.y = u2f_hi(v.z);
        f1.z = u2f(v.w); f1.w = u2f_hi(v.w);
      }
      float* dst = &tile[(ch * 6 + rr) * TW + 4 + c8 * 8];
      *(float4*)dst = f0;
      *(float4*)(dst + 4) = f1;
    }
    for (int i = tid; i < 16 * 6 * 2; i += 256) {
      int ch = i / 12;
      int rem = i - ch * 12;
      int rr = rem >> 1, side = rem & 1;
      tile[(ch * 6 + rr) * TW + (side ? 132 : 3)] = 0.f;
    }
  };

  stage(kch);
  __syncthreads();

  float2 logits[9];
#pragma unroll
  for (int a = 0; a < 9; a++) logits[a] = {0.f, 0.f};

#pragma unroll 4
  for (int d = 0; d < 16; d++) {
    float pt[3][4];
#pragma unroll
    for (int ry = 0; ry < 3; ry++) {
      const float* rowp = &tile[(d * 6 + r + ry) * TW + 3 + c0];
#pragma unroll
      for (int cc = 0; cc < 4; cc++) pt[ry][cc] = rowp[cc];
    }
    unsigned int qu = *(const unsigned int*)(Yb + (size_t)(qch + d) * HW + p0);
    float2 qv = {0.25f * u2f(qu), 0.25f * u2f_hi(qu)};
#pragma unroll
    for (int a = 0; a < 9; a++) {
      const float* wr = dep_w + (d * 9 + a) * 9;   // uniform -> s_load
      float bb = dep_b[d * 9 + a];
      float2 tt = {bb, bb};
#pragma unroll
      for (int ky = 0; ky < 3; ky++)
#pragma unroll
        for (int kx = 0; kx < 3; kx++) {
          float wv = wr[ky * 3 + kx];
          tt.x += wv * pt[ky][kx];
          tt.y += wv * pt[ky][kx + 1];
        }
      logits[a].x += qv.x * tt.x;
      logits[a].y += qv.y * tt.y;
    }
  }

  float2 aw[9];
  {
    float2 m = logits[0];
#pragma unroll
    for (int a = 1; a < 9; a++) {
      m.x = fmaxf(m.x, logits[a].x);
      m.y = fmaxf(m.y, logits[a].y);
    }
    float2 ssum = {0.f, 0.f};
#pragma unroll
    for (int a = 0; a < 9; a++) {
      aw[a].x = __expf(logits[a].x - m.x);
      aw[a].y = __expf(logits[a].y - m.y);
      ssum.x += aw[a].x; ssum.y += aw[a].y;
    }
    float2 inv = {1.f / ssum.x, 1.f / ssum.y};
#pragma unroll
    for (int a = 0; a < 9; a++) { aw[a].x *= inv.x; aw[a].y *= inv.y; }
  }

  __syncthreads();
  stage(vch);
  __syncthreads();

  ushort_t ou[2][16];
#pragma unroll 4
  for (int d = 0; d < 16; d++) {
    float pt[3][4];
#pragma unroll
    for (int ry = 0; ry < 3; ry++) {
      const float* rowp = &tile[(d * 6 + r + ry) * TW + 3 + c0];
#pragma unroll
      for (int cc = 0; cc < 4; cc++) pt[ry][cc] = rowp[cc];
    }
    float2 o = {0.f, 0.f};
#pragma unroll
    for (int a = 0; a < 9; a++) {
      const float* wr = dep_w + (d * 9 + a) * 9;
      float bb = dep_b[d * 9 + a];
      float2 tt = {bb, bb};
#pragma unroll
      for (int ky = 0; ky < 3; ky++)
#pragma unroll
        for (int kx = 0; kx < 3; kx++) {
          float wv = wr[ky * 3 + kx];
          tt.x += wv * pt[ky][kx];
          tt.y += wv * pt[ky][kx + 1];
        }
      o.x += aw[a].x * tt.x;
      o.y += aw[a].y * tt.y;
    }
    ou[0][d] = f2bu(o.x);
    ou[1][d] = f2bu(o.y);
  }
  ushort_t* dst0 = att_t + (((size_t)(b * 2 + sp)) * HW + p0) * 128 + n * 16;
  *(uint4*)(dst0) = *(uint4*)&ou[0][0];
  *(uint4*)(dst0 + 8) = *(uint4*)&ou[0][8];
  *(uint4*)(dst0 + 128) = *(uint4*)&ou[1][0];
  *(uint4*)(dst0 + 136) = *(uint4*)&ou[1][8];
}

// ---------------------------------------------------------------- 1x1 proj as MFMA GEMM
__global__ __launch_bounds__(256) void k_proj_mfma(
    const ushort_t* __restrict__ att_t, const ushort_t* __restrict__ wproj,
    const float* __restrict__ bpack, float* __restrict__ out, int B) {
  __shared__ ushort_t As[128 * 32];   // [co][k]
  __shared__ ushort_t Bs[128 * 32];   // [px][k]
  int tid = threadIdx.x;
  int lane = tid & 63;
  int wid = tid >> 6;
  int px0 = blockIdx.x * 128;
  int bsp = blockIdx.z;            // b*2+sp
  int b = bsp >> 1, sp = bsp & 1;

  int wm = (wid >> 1) * 64, wn = (wid & 1) * 64;
  int l15 = lane & 15, q = lane >> 4, kq = q * 8;
  int lrow = lane >> 2;
  int lq = lane & 3;

  f32x4 acc[4][4];
#pragma unroll
  for (int i = 0; i < 4; i++)
#pragma unroll
    for (int j = 0; j < 4; j++) acc[i][j] = (f32x4){0.f, 0.f, 0.f, 0.f};

  const ushort_t* aSrc = wproj + (size_t)(sp * 128 + wid * 32 + lrow) * 128 + lq * 8;
  const ushort_t* bSrc = att_t + ((size_t)bsp * HW + px0 + wid * 32 + lrow) * 128 + lq * 8;
  ushort_t* aDst0 = &As[(wid * 32) * 32];
  ushort_t* aDst1 = &As[(wid * 32 + 16) * 32];
  ushort_t* bDst0 = &Bs[(wid * 32) * 32];
  ushort_t* bDst1 = &Bs[(wid * 32 + 16) * 32];

  for (int ci0 = 0; ci0 < 128; ci0 += 32) {
    __syncthreads();
    gl_lds16(aSrc + ci0, aDst0);
    gl_lds16(aSrc + ci0 + (size_t)16 * 128, aDst1);
    gl_lds16(bSrc + ci0, bDst0);
    gl_lds16(bSrc + ci0 + (size_t)16 * 128, bDst1);
    __syncthreads();
    bf16x8 af[4], bv[4];
#pragma unroll
    for (int t = 0; t < 4; t++)
      af[t] = *(const bf16x8*)&As[(wm + t * 16 + l15) * 32 + kq];
#pragma unroll
    for (int t = 0; t < 4; t++)
      bv[t] = *(const bf16x8*)&Bs[(wn + t * 16 + l15) * 32 + kq];
#pragma unroll
    for (int i = 0; i < 4; i++)
#pragma unroll
      for (int j = 0; j < 4; j++)
        acc[i][j] = __builtin_amdgcn_mfma_f32_16x16x32_bf16(af[i], bv[j],
                                                            acc[i][j], 0, 0, 0);
  }

  float* ob = out + (size_t)sp * B * DIMC * HW + (size_t)b * DIMC * HW;
#pragma unroll
  for (int i = 0; i < 4; i++) {
    int corow = wm + i * 16 + q * 4;
#pragma unroll
    for (int j = 0; j < 4; j++) {
      int px = px0 + wn + j * 16 + l15;
#pragma unroll
      for (int r = 0; r < 4; r++)
        ob[(size_t)(corow + r) * HW + px] =
            acc[i][j][r] + bpack[640 + sp * 128 + corow + r];
    }
  }
}

// ---------------------------------------------------------------- launch
extern "C" void kernel_launch(void* const* d_in, const int* in_sizes, int n_in,
                              void* d_out, int out_size, void* d_ws, size_t ws_size,
                              hipStream_t stream) {
  const float* x = (const float*)d_in[0];
  const float* ms = (const float*)d_in[1];
  const float* lpan = (const float*)d_in[2];
  const float* pan = (const float*)d_in[3];
  const float* s = (const float*)d_in[4];
  const float* q_w = (const float*)d_in[5];
  const float* q_b = (const float*)d_in[6];
  const float* k_pan_w = (const float*)d_in[7];
  const float* k_pan_b = (const float*)d_in[8];
  const float* v_pan_w = (const float*)d_in[9];
  const float* v_pan_b = (const float*)d_in[10];
  const float* kv_ms_w = (const float*)d_in[11];
  const float* kv_ms_b = (const float*)d_in[12];
  const float* dep_w = (const float*)d_in[13];
  const float* dep_b = (const float*)d_in[14];
  const float* pp_w = (const float*)d_in[15];
  const float* pp_b = (const float*)d_in[16];
  const float* pm_w = (const float*)d_in[17];
  const float* pm_b = (const float*)d_in[18];
  int B = in_sizes[0] / (DIMC * HW);

  char* ws = (char*)d_ws;
  size_t off = 0;
  auto alloc = [&](size_t bytes) -> void* {
    void* pptr = ws + off;
    off = (off + bytes + 255) & ~(size_t)255;
    return pptr;
  };
  ushort_t* wp2 = (ushort_t*)alloc((size_t)COUT * KTOT * sizeof(ushort_t));
  ushort_t* wproj = (ushort_t*)alloc((size_t)2 * 128 * 128 * sizeof(ushort_t));
  float* bpack = (float*)alloc((size_t)(COUT + 256) * sizeof(float));
  bf16* Y = (bf16*)alloc((size_t)B * COUT * HW * sizeof(bf16));
  // X_T and att_t share the tail region: X_T dead after conv, att_t written after.
  size_t xt_sz = (size_t)B * NPIX * CI_PAD * sizeof(ushort_t);
  size_t att_sz = (size_t)B * 2 * HW * 128 * sizeof(ushort_t);
  ushort_t* xt = (ushort_t*)(ws + off);
  ushort_t* att_t = (ushort_t*)(ws + off);
  off += (att_sz > xt_sz ? att_sz : xt_sz);
  (void)ws_size; (void)n_in; (void)out_size;

  k_prep<<<dim3(2, HSZ + 2, B), 256, 0, stream>>>(x, ms, lpan, pan, s, xt, B);
  k_pack<<<dim3((COUT * CI_PAD + 255) / 256), 256, 0, stream>>>(
      q_w, q_b, k_pan_w, k_pan_b, v_pan_w, v_pan_b, kv_ms_w, kv_ms_b,
      pp_w, pp_b, pm_w, pm_b, wp2, wproj, bpack);
  k_conv_mfma<<<dim3(HSZ, COUT / 128, B), 256, 0, stream>>>(xt, wp2, bpack, Y, B);
  k_attn<<<dim3(HSZ / 4, 2 * NH, B), 256, 0, stream>>>(Y, dep_w, dep_b, att_t, B);
  k_proj_mfma<<<dim3(HW / 128, 1, 2 * B), 256, 0, stream>>>(att_t, wproj, bpack,
                                                            (float*)d_out, B);
}